// Round 11
// baseline (163.020 us; speedup 1.0000x reference)
//
#include <hip/hip_runtime.h>

// MHA: B=4, S=2048, D=512, H=8, DH=64. fp32 in/out, f16 MFMA internally.
typedef _Float16 half8  __attribute__((ext_vector_type(8)));
typedef _Float16 half4v __attribute__((ext_vector_type(4)));
typedef _Float16 half2v __attribute__((ext_vector_type(2)));
typedef __fp16   fp16x2 __attribute__((ext_vector_type(2)));
typedef float    float4v __attribute__((ext_vector_type(4)));

#define CSC 0.18033688f  /* DH^-0.5 * log2(e) */

__device__ __forceinline__ void async16(const _Float16* g, void* l) {
    __builtin_amdgcn_global_load_lds((const __attribute__((address_space(1))) void*)g,
                                     (__attribute__((address_space(3))) void*)l, 16, 0, 0);
}

__device__ __forceinline__ half2v pk2(float a, float b) {
    return __builtin_bit_cast(half2v, __builtin_amdgcn_cvt_pkrtz(a, b));
}

// ---------------- fused prep: blocks [0,4096) cast x -> f16; [4096,4288) transpose W ----------------
__global__ __launch_bounds__(256) void mha_prep(const float* __restrict__ x,
    const float* __restrict__ wq, const float* __restrict__ wk, const float* __restrict__ wv,
    _Float16* __restrict__ xh, _Float16* __restrict__ wt) {
    __shared__ __align__(16) _Float16 T[64][72];  // [dh][dl], padded (W branch only)
    const int tid = threadIdx.x;
    if (blockIdx.x < 4096) {
        int t = blockIdx.x * 256 + tid;  // 1048576 float4s
        float4v v = ((const float4v*)x)[t];
        half4v o;
        #pragma unroll
        for (int i = 0; i < 4; ++i) o[i] = (_Float16)v[i];
        ((half4v*)xh)[t] = o;
        return;
    }
    const int blk = blockIdx.x - 4096;        // 192 = mat(3) x h(8) x dtile(8)
    const int dt = blk & 7, h = (blk >> 3) & 7, mat = blk >> 6;
    const float* w = ((mat == 0) ? wq : (mat == 1) ? wk : wv) + h * 32768 + dt * 64 * 64;
    #pragma unroll
    for (int i = 0; i < 4; ++i) {
        int s = tid + i * 256;                // 0..1023: dl = s>>4, c4 = s&15
        int dl = s >> 4, c4 = s & 15;
        float4v v = ((const float4v*)(w + (size_t)dl * 64))[c4];
        #pragma unroll
        for (int e = 0; e < 4; ++e) T[c4 * 4 + e][dl] = (_Float16)v[e];
    }
    __syncthreads();
    #pragma unroll
    for (int i = 0; i < 2; ++i) {
        int s = tid + i * 256;                // 0..511: dh = s>>3, c8 = s&7
        int dh = s >> 3, c8 = s & 7;
        half8 o;
        #pragma unroll
        for (int e = 0; e < 8; ++e) o[e] = T[dh][c8 * 8 + e];
        *(half8*)(wt + (size_t)((mat * 8 + h) * 64 + dh) * 512 + dt * 64 + c8 * 8) = o;
    }
}

// ---------------- QKV projection: C[8192][1536] = xh[8192][512] * Wt^T ----------------
__global__ __launch_bounds__(256, 3) void mha_qkv(const _Float16* __restrict__ xh,
    const _Float16* __restrict__ wt, _Float16* __restrict__ Qm, _Float16* __restrict__ Km,
    _Float16* __restrict__ Vt) {
    __shared__ __align__(16) _Float16 Ash[2][128 * 32];
    __shared__ __align__(16) _Float16 Bsh[2][128 * 32];
    const int tid = threadIdx.x;
    const int lane = tid & 63, wave = tid >> 6;
    const int quad = lane >> 4, li = lane & 15;
    const int m0 = blockIdx.x * 128, n0 = blockIdx.y * 128;
    float4v acc[4][4] = {};
    const int r0 = tid >> 2, c0 = (tid & 3) ^ ((r0 >> 1) & 3);
    const int s1 = 256 + tid, r1 = s1 >> 2, c1 = (s1 & 3) ^ ((r1 >> 1) & 3);
    const _Float16* gA0 = xh + (size_t)(m0 + r0) * 512 + c0 * 8;
    const _Float16* gA1 = xh + (size_t)(m0 + r1) * 512 + c1 * 8;
    const _Float16* gB0 = wt + (size_t)(n0 + r0) * 512 + c0 * 8;
    const _Float16* gB1 = wt + (size_t)(n0 + r1) * 512 + c1 * 8;
    const int wr = (wave >> 1) * 64, wc = (wave & 1) * 64;
    const char* aB[2]; const char* bB[2];
    #pragma unroll
    for (int bb = 0; bb < 2; ++bb) {
        aB[bb] = (const char*)Ash[bb] + (wr + li) * 64 + ((quad ^ ((li >> 1) & 3)) << 4);
        bB[bb] = (const char*)Bsh[bb] + (wc + li) * 64 + ((quad ^ ((li >> 1) & 3)) << 4);
    }
    auto stage = [&](int bb, int kk) {
        async16(gA0 + kk, (char*)Ash[bb] + wave * 1024);
        async16(gA1 + kk, (char*)Ash[bb] + 4096 + wave * 1024);
        async16(gB0 + kk, (char*)Bsh[bb] + wave * 1024);
        async16(gB1 + kk, (char*)Bsh[bb] + 4096 + wave * 1024);
    };
    auto compute = [&](int bb) {
        half8 af[4], bf[4];
        #pragma unroll
        for (int mt = 0; mt < 4; ++mt) af[mt] = *(const half8*)(aB[bb] + mt * 1024);
        #pragma unroll
        for (int nt = 0; nt < 4; ++nt) bf[nt] = *(const half8*)(bB[bb] + nt * 1024);
        #pragma unroll
        for (int mt = 0; mt < 4; ++mt)
            #pragma unroll
            for (int nt = 0; nt < 4; ++nt)
                acc[mt][nt] = __builtin_amdgcn_mfma_f32_16x16x32_f16(af[mt], bf[nt], acc[mt][nt], 0, 0, 0);
    };
    stage(0, 0);
    for (int kk = 0; kk < 512; kk += 64) {
        __syncthreads();
        stage(1, kk + 32);
        compute(0);
        __syncthreads();
        if (kk + 64 < 512) stage(0, kk + 64);
        compute(1);
    }
    const int mat = n0 >> 9;  // 0=Q 1=K 2=V (uniform per block)
    const float osc = (mat == 0) ? CSC : 1.0f;  // fold scale*log2e into Q
    #pragma unroll
    for (int mt = 0; mt < 4; ++mt) {
        int m = m0 + wr + mt * 16 + quad * 4;  // + reg
        int b = m >> 11, s = m & 2047;
        #pragma unroll
        for (int nt = 0; nt < 4; ++nt) {
            int n = n0 + wc + nt * 16 + li;
            int h = (n >> 6) & 7, dh = n & 63;
            int bh = b * 8 + h;
            if (mat == 2) {  // V^T[bh][dh][s]
                half4v pkv;
                #pragma unroll
                for (int r = 0; r < 4; ++r) pkv[r] = (_Float16)acc[mt][nt][r];
                *(half4v*)(Vt + ((size_t)bh * 64 + dh) * 2048 + s) = pkv;
            } else {  // Q/K [bh][s][dh]
                _Float16* dst = (mat == 0) ? Qm : Km;
                size_t base = ((size_t)bh * 2048 + s) * 64 + dh;
                #pragma unroll
                for (int r = 0; r < 4; ++r) dst[base + (size_t)r * 64] = (_Float16)(acc[mt][nt][r] * osc);
            }
        }
    }
}

// ---------------- flash attention: R9 structure, V direct from L2 (no LDS for V) ----------------
// K: LDS dbuf 128-kpos tiles (K-row perm -> PV@K=32). V: PV B-operand frags loaded straight
// from global V^T (L2-resident via XCD swizzle; 16 rows x 64B per wave instr, coalesced).
// Halves LDS reads + staging + barrier drain vs R9.
__global__ __launch_bounds__(256, 2) void mha_attn(const _Float16* __restrict__ Qm,
    const _Float16* __restrict__ Km, const _Float16* __restrict__ Vt, float* __restrict__ out) {
    __shared__ __align__(16) _Float16 KtA[2][128 * 64];   // [buf][kpos][d], swizzled, 16KB each
    const int tid = threadIdx.x, lane = tid & 63, wave = tid >> 6;
    const int quad = lane >> 4, li = lane & 15;
    const int flat = blockIdx.x;
    const int qb = (flat >> 3) & 15;
    const int bh = ((flat >> 7) << 3) | (flat & 7);
    const int b = bh >> 3, h = bh & 7;
    const _Float16* Qg = Qm + (size_t)bh * 2048 * 64;
    const _Float16* Kg = Km + (size_t)bh * 2048 * 64;
    const _Float16* Vg = Vt + (size_t)bh * 64 * 2048;
    const int q0 = qb * 128 + wave * 32;  // wave handles 32 q (2 tiles of 16)
    // Q (pre-scaled by CSC) as B-operand (n=q=lane&15, k=d=quad*8+j)
    half8 qf[2][2];
    #pragma unroll
    for (int qt = 0; qt < 2; ++qt)
        #pragma unroll
        for (int ds = 0; ds < 2; ++ds)
            qf[qt][ds] = *(const half8*)(Qg + (size_t)(q0 + qt * 16 + li) * 64 + ds * 32 + quad * 8);
    float4v O[2][4] = {};
    float lsum[2] = {0.f, 0.f};
    // K staging: swizzle swk(r) = (r&3) | (((r>>3)&1)<<2)
    const _Float16* pK[4];
    #pragma unroll
    for (int is = 0; is < 4; ++is) {
        int s = is * 256 + tid;
        int rk = s >> 3, sck = s & 7;
        int swk = (rk & 3) | (((rk >> 3) & 1) << 2);
        pK[is] = Kg + (size_t)rk * 64 + (sck ^ swk) * 8;
    }
    auto stage = [&](int bb) {
        #pragma unroll
        for (int is = 0; is < 4; ++is) {
            async16(pK[is], (char*)KtA[bb] + is * 4096 + wave * 1024);
            pK[is] += 8192;  // next 128 kpos rows
        }
    };
    // V direct-global lane pointers: row d = dt*16 + li, col chunk quad*8; advance 128 kpos/tile
    const _Float16* vP[4];
    #pragma unroll
    for (int dt = 0; dt < 4; ++dt) vP[dt] = Vg + (size_t)(dt * 16 + li) * 2048 + quad * 8;
    // hoisted permuted K LDS read bases (K-row permutation: PV runs at K=32)
    const int rowE = ((li >> 2) << 3) | (li & 3);
    const int swzE = (li & 3) | (((li >> 2) & 1) << 2);
    const char *k0e[2], *k1e[2];
    #pragma unroll
    for (int bb = 0; bb < 2; ++bb) {
        const char* base = (const char*)KtA[bb] + rowE * 128;
        k0e[bb] = base + ((quad ^ swzE) << 4);
        k1e[bb] = base + (((quad + 4) ^ swzE) << 4);
    }
    auto compute = [&](int bb) {
        #pragma unroll
        for (int c = 0; c < 4; ++c) {
            // V frags for this c: issue first so L2 latency overlaps QK MFMA + exp
            half8 vf[4];
            #pragma unroll
            for (int dt = 0; dt < 4; ++dt) vf[dt] = *(const half8*)(vP[dt] + c * 32);
            half8 f0e = *(const half8*)(k0e[bb] + c * 4096);
            half8 f1e = *(const half8*)(k1e[bb] + c * 4096);
            half8 f0o = *(const half8*)(k0e[bb] + c * 4096 + 512);
            half8 f1o = *(const half8*)(k1e[bb] + c * 4096 + 512);
            float4v se[2] = {}, so[2] = {};
            se[0] = __builtin_amdgcn_mfma_f32_16x16x32_f16(f0e, qf[0][0], se[0], 0, 0, 0);
            se[0] = __builtin_amdgcn_mfma_f32_16x16x32_f16(f1e, qf[0][1], se[0], 0, 0, 0);
            se[1] = __builtin_amdgcn_mfma_f32_16x16x32_f16(f0e, qf[1][0], se[1], 0, 0, 0);
            se[1] = __builtin_amdgcn_mfma_f32_16x16x32_f16(f1e, qf[1][1], se[1], 0, 0, 0);
            so[0] = __builtin_amdgcn_mfma_f32_16x16x32_f16(f0o, qf[0][0], so[0], 0, 0, 0);
            so[0] = __builtin_amdgcn_mfma_f32_16x16x32_f16(f1o, qf[0][1], so[0], 0, 0, 0);
            so[1] = __builtin_amdgcn_mfma_f32_16x16x32_f16(f0o, qf[1][0], so[1], 0, 0, 0);
            so[1] = __builtin_amdgcn_mfma_f32_16x16x32_f16(f1o, qf[1][1], so[1], 0, 0, 0);
            half8 pf[2];
            #pragma unroll
            for (int qt = 0; qt < 2; ++qt) {
                float pe[4], po[4];
                #pragma unroll
                for (int r = 0; r < 4; ++r) {
                    pe[r] = __builtin_amdgcn_exp2f(se[qt][r]);
                    po[r] = __builtin_amdgcn_exp2f(so[qt][r]);
                    lsum[qt] += pe[r] + po[r];
                }
                half4v a = __builtin_shufflevector(pk2(pe[0], pe[1]), pk2(pe[2], pe[3]), 0, 1, 2, 3);
                half4v o = __builtin_shufflevector(pk2(po[0], po[1]), pk2(po[2], po[3]), 0, 1, 2, 3);
                pf[qt] = __builtin_shufflevector(a, o, 0, 1, 2, 3, 4, 5, 6, 7);
            }
            #pragma unroll
            for (int dt = 0; dt < 4; ++dt) {
                O[0][dt] = __builtin_amdgcn_mfma_f32_16x16x32_f16(pf[0], vf[dt], O[0][dt], 0, 0, 0);
                O[1][dt] = __builtin_amdgcn_mfma_f32_16x16x32_f16(pf[1], vf[dt], O[1][dt], 0, 0, 0);
            }
        }
        #pragma unroll
        for (int dt = 0; dt < 4; ++dt) vP[dt] += 128;  // next 128 kpos
    };
    stage(0);
    for (int it = 0; it < 8; ++it) {
        __syncthreads();
        stage(1);
        compute(0);
        __syncthreads();
        if (it < 7) stage(0);
        compute(1);
    }
    // epilogue: cross-quad l reduction, then out = O/l
    #pragma unroll
    for (int qt = 0; qt < 2; ++qt) {
        float l = lsum[qt];
        l += __shfl_xor(l, 16);
        l += __shfl_xor(l, 32);
        #pragma unroll
        for (int r = 0; r < 4; ++r) {
            float lr = __shfl(l, quad * 4 + r);
            float inv = 1.0f / lr;
            int q = q0 + qt * 16 + quad * 4 + r;
            float* orow = out + ((size_t)(b * 2048 + q)) * 512 + h * 64;
            #pragma unroll
            for (int dt = 0; dt < 4; ++dt) orow[dt * 16 + li] = O[qt][dt][r] * inv;
        }
    }
}

extern "C" void kernel_launch(void* const* d_in, const int* in_sizes, int n_in,
                              void* d_out, int out_size, void* d_ws, size_t ws_size,
                              hipStream_t stream) {
    const float* x  = (const float*)d_in[0];
    const float* wq = (const float*)d_in[1];
    const float* wk = (const float*)d_in[2];
    const float* wv = (const float*)d_in[3];
    float* out = (float*)d_out;
    char* ws = (char*)d_ws;
    // ws layout (bytes): xh 8M | Wt 1.5M | Q 8M | K 8M | Vt 8M  = 35,127,296 total
    _Float16* xh = (_Float16*)(ws);
    _Float16* wt = (_Float16*)(ws + 8388608);
    _Float16* Qm = (_Float16*)(ws + 9961472);
    _Float16* Km = (_Float16*)(ws + 18350080);
    _Float16* Vt = (_Float16*)(ws + 26738688);
    if (ws_size < 35127296u) return;
    mha_prep<<<4288, 256, 0, stream>>>(x, wq, wk, wv, xh, wt);
    mha_qkv<<<dim3(64, 12), 256, 0, stream>>>(xh, wt, Qm, Km, Vt);
    mha_attn<<<512, 256, 0, stream>>>(Qm, Km, Vt, out);
}

// Round 12
// 135.788 us; speedup vs baseline: 1.2005x; 1.2005x over previous
//
#include <hip/hip_runtime.h>

// MHA: B=4, S=2048, D=512, H=8, DH=64. fp32 in/out, f16 MFMA internally.
typedef _Float16 half8  __attribute__((ext_vector_type(8)));
typedef _Float16 half4v __attribute__((ext_vector_type(4)));
typedef _Float16 half2v __attribute__((ext_vector_type(2)));
typedef __fp16   fp16x2 __attribute__((ext_vector_type(2)));
typedef float    float4v __attribute__((ext_vector_type(4)));

#define CSC 0.18033688f  /* DH^-0.5 * log2(e) */

__device__ __forceinline__ void async16(const _Float16* g, void* l) {
    __builtin_amdgcn_global_load_lds((const __attribute__((address_space(1))) void*)g,
                                     (__attribute__((address_space(3))) void*)l, 16, 0, 0);
}

__device__ __forceinline__ half2v pk2(float a, float b) {
    return __builtin_bit_cast(half2v, __builtin_amdgcn_cvt_pkrtz(a, b));
}

// ---------------- fused prep: blocks [0,4096) cast x -> f16; [4096,4288) transpose W ----------------
__global__ __launch_bounds__(256) void mha_prep(const float* __restrict__ x,
    const float* __restrict__ wq, const float* __restrict__ wk, const float* __restrict__ wv,
    _Float16* __restrict__ xh, _Float16* __restrict__ wt) {
    __shared__ __align__(16) _Float16 T[64][72];  // [dh][dl], padded (W branch only)
    const int tid = threadIdx.x;
    if (blockIdx.x < 4096) {
        int t = blockIdx.x * 256 + tid;  // 1048576 float4s
        float4v v = ((const float4v*)x)[t];
        half4v o;
        #pragma unroll
        for (int i = 0; i < 4; ++i) o[i] = (_Float16)v[i];
        ((half4v*)xh)[t] = o;
        return;
    }
    const int blk = blockIdx.x - 4096;        // 192 = mat(3) x h(8) x dtile(8)
    const int dt = blk & 7, h = (blk >> 3) & 7, mat = blk >> 6;
    const float* w = ((mat == 0) ? wq : (mat == 1) ? wk : wv) + h * 32768 + dt * 64 * 64;
    #pragma unroll
    for (int i = 0; i < 4; ++i) {
        int s = tid + i * 256;                // 0..1023: dl = s>>4, c4 = s&15
        int dl = s >> 4, c4 = s & 15;
        float4v v = ((const float4v*)(w + (size_t)dl * 64))[c4];
        #pragma unroll
        for (int e = 0; e < 4; ++e) T[c4 * 4 + e][dl] = (_Float16)v[e];
    }
    __syncthreads();
    #pragma unroll
    for (int i = 0; i < 2; ++i) {
        int s = tid + i * 256;                // 0..511: dh = s>>3, c8 = s&7
        int dh = s >> 3, c8 = s & 7;
        half8 o;
        #pragma unroll
        for (int e = 0; e < 8; ++e) o[e] = T[dh][c8 * 8 + e];
        *(half8*)(wt + (size_t)((mat * 8 + h) * 64 + dh) * 512 + dt * 64 + c8 * 8) = o;
    }
}

// ---------------- QKV projection: C[8192][1536] = xh[8192][512] * Wt^T ----------------
__global__ __launch_bounds__(256, 3) void mha_qkv(const _Float16* __restrict__ xh,
    const _Float16* __restrict__ wt, _Float16* __restrict__ Qm, _Float16* __restrict__ Km,
    _Float16* __restrict__ Vt) {
    __shared__ __align__(16) _Float16 Ash[2][128 * 32];
    __shared__ __align__(16) _Float16 Bsh[2][128 * 32];
    const int tid = threadIdx.x;
    const int lane = tid & 63, wave = tid >> 6;
    const int quad = lane >> 4, li = lane & 15;
    const int m0 = blockIdx.x * 128, n0 = blockIdx.y * 128;
    float4v acc[4][4] = {};
    const int r0 = tid >> 2, c0 = (tid & 3) ^ ((r0 >> 1) & 3);
    const int s1 = 256 + tid, r1 = s1 >> 2, c1 = (s1 & 3) ^ ((r1 >> 1) & 3);
    const _Float16* gA0 = xh + (size_t)(m0 + r0) * 512 + c0 * 8;
    const _Float16* gA1 = xh + (size_t)(m0 + r1) * 512 + c1 * 8;
    const _Float16* gB0 = wt + (size_t)(n0 + r0) * 512 + c0 * 8;
    const _Float16* gB1 = wt + (size_t)(n0 + r1) * 512 + c1 * 8;
    const int wr = (wave >> 1) * 64, wc = (wave & 1) * 64;
    const char* aB[2]; const char* bB[2];
    #pragma unroll
    for (int bb = 0; bb < 2; ++bb) {
        aB[bb] = (const char*)Ash[bb] + (wr + li) * 64 + ((quad ^ ((li >> 1) & 3)) << 4);
        bB[bb] = (const char*)Bsh[bb] + (wc + li) * 64 + ((quad ^ ((li >> 1) & 3)) << 4);
    }
    auto stage = [&](int bb, int kk) {
        async16(gA0 + kk, (char*)Ash[bb] + wave * 1024);
        async16(gA1 + kk, (char*)Ash[bb] + 4096 + wave * 1024);
        async16(gB0 + kk, (char*)Bsh[bb] + wave * 1024);
        async16(gB1 + kk, (char*)Bsh[bb] + 4096 + wave * 1024);
    };
    auto compute = [&](int bb) {
        half8 af[4], bf[4];
        #pragma unroll
        for (int mt = 0; mt < 4; ++mt) af[mt] = *(const half8*)(aB[bb] + mt * 1024);
        #pragma unroll
        for (int nt = 0; nt < 4; ++nt) bf[nt] = *(const half8*)(bB[bb] + nt * 1024);
        #pragma unroll
        for (int mt = 0; mt < 4; ++mt)
            #pragma unroll
            for (int nt = 0; nt < 4; ++nt)
                acc[mt][nt] = __builtin_amdgcn_mfma_f32_16x16x32_f16(af[mt], bf[nt], acc[mt][nt], 0, 0, 0);
    };
    stage(0, 0);
    for (int kk = 0; kk < 512; kk += 64) {
        __syncthreads();
        stage(1, kk + 32);
        compute(0);
        __syncthreads();
        if (kk + 64 < 512) stage(0, kk + 64);
        compute(1);
    }
    const int mat = n0 >> 9;  // 0=Q 1=K 2=V (uniform per block)
    const float osc = (mat == 0) ? CSC : 1.0f;  // fold scale*log2e into Q
    #pragma unroll
    for (int mt = 0; mt < 4; ++mt) {
        int m = m0 + wr + mt * 16 + quad * 4;  // + reg
        int b = m >> 11, s = m & 2047;
        #pragma unroll
        for (int nt = 0; nt < 4; ++nt) {
            int n = n0 + wc + nt * 16 + li;
            int h = (n >> 6) & 7, dh = n & 63;
            int bh = b * 8 + h;
            if (mat == 2) {  // V^T[bh][dh][s]
                half4v pkv;
                #pragma unroll
                for (int r = 0; r < 4; ++r) pkv[r] = (_Float16)acc[mt][nt][r];
                *(half4v*)(Vt + ((size_t)bh * 64 + dh) * 2048 + s) = pkv;
            } else {  // Q/K [bh][s][dh]
                _Float16* dst = (mat == 0) ? Qm : Km;
                size_t base = ((size_t)bh * 2048 + s) * 64 + dh;
                #pragma unroll
                for (int r = 0; r < 4; ++r) dst[base + (size_t)r * 64] = (_Float16)(acc[mt][nt][r] * osc);
            }
        }
    }
}

// ---------------- flash attention: split-K + q_wave=64 ----------------
// No-rescale softmax => kpos-partials merge by plain addition. Block = 4 waves:
// wave w -> q-half (w>>1, 64 q) x kpos-half (w&1, 1024 kpos). Two LDS tile streams
// (64-kpos tiles, dbuf, 64KB total) -> 2 blocks/CU = 8 waves/CU with q_wave=64:
// per-CU ds_read traffic HALVES vs R9. Merge through tile LDS after the K-loop.
// Tile formulas (64-row K perm/swizzle, 64-col V) verified in R10.
__global__ __launch_bounds__(256, 2) void mha_attn(const _Float16* __restrict__ Qm,
    const _Float16* __restrict__ Km, const _Float16* __restrict__ Vt, float* __restrict__ out) {
    __shared__ __align__(16) _Float16 KtA[4][64 * 64];   // [stream*2+buf][kpos][d], 8KB each
    __shared__ __align__(16) _Float16 VtA[4][64 * 64];   // [stream*2+buf][d][kpos], 8KB each
    const int tid = threadIdx.x, lane = tid & 63, wave = tid >> 6;
    const int quad = lane >> 4, li = lane & 15;
    const int strm = wave & 1, hh = wave >> 1;
    const int flat = blockIdx.x;
    const int qb = (flat >> 3) & 15;
    const int bh = ((flat >> 7) << 3) | (flat & 7);
    const int b = bh >> 3, h = bh & 7;
    const _Float16* Qg = Qm + (size_t)bh * 2048 * 64;
    const _Float16* Kg = Km + (size_t)bh * 2048 * 64 + (size_t)strm * 1024 * 64;
    const _Float16* Vg = Vt + (size_t)bh * 64 * 2048 + (size_t)strm * 1024;
    const int q0 = qb * 128 + hh * 64;  // wave handles 64 q (4 tiles of 16)
    // Q (pre-scaled by CSC) as B-operand (n=q=lane&15, k=d=quad*8+j)
    half8 qf[4][2];
    #pragma unroll
    for (int qt = 0; qt < 4; ++qt)
        #pragma unroll
        for (int ds = 0; ds < 2; ++ds)
            qf[qt][ds] = *(const half8*)(Qg + (size_t)(q0 + qt * 16 + li) * 64 + ds * 32 + quad * 8);
    float4v O[4][4] = {};
    float lsum[4] = {0.f, 0.f, 0.f, 0.f};
    char* Kst[2]; char* Vst[2];
    #pragma unroll
    for (int bb = 0; bb < 2; ++bb) {
        Kst[bb] = (char*)KtA + (strm * 2 + bb) * 8192;
        Vst[bb] = (char*)VtA + (strm * 2 + bb) * 8192;
    }
    // staging: per stream 512 chunks/tile, 2 waves x 4 issues. K swz swk(r)=(r&3)|(((r>>3)&1)<<2); V swz r&7
    const _Float16* pK[4]; const _Float16* pV[4];
    #pragma unroll
    for (int is = 0; is < 4; ++is) {
        int c = is * 128 + hh * 64 + lane;    // chunk 0..511
        int rk = c >> 3, sck = c & 7;
        int swk = (rk & 3) | (((rk >> 3) & 1) << 2);
        int rv = c >> 3, cv = (c & 7) ^ (rv & 7);
        pK[is] = Kg + (size_t)rk * 64 + (sck ^ swk) * 8;
        pV[is] = Vg + (size_t)rv * 2048 + cv * 8;
    }
    auto stage = [&](int bb) {
        #pragma unroll
        for (int is = 0; is < 4; ++is) {
            async16(pK[is], Kst[bb] + is * 2048 + hh * 1024);
            async16(pV[is], Vst[bb] + is * 2048 + hh * 1024);
            pK[is] += 4096;  // next 64 kpos rows
            pV[is] += 64;    // next 64 kpos cols
        }
    };
    // hoisted permuted K LDS read bases (K-row permutation: PV runs at K=32) + V bases
    const int rowE = ((li >> 2) << 3) | (li & 3);
    const int swzE = (li & 3) | (((li >> 2) & 1) << 2);
    const char *k0e[2], *k1e[2], *vBq[2];
    #pragma unroll
    for (int bb = 0; bb < 2; ++bb) {
        k0e[bb] = Kst[bb] + rowE * 128 + ((quad ^ swzE) << 4);
        k1e[bb] = Kst[bb] + rowE * 128 + (((quad + 4) ^ swzE) << 4);
        vBq[bb] = Vst[bb] + li * 128;
    }
    int coff[2];
    #pragma unroll
    for (int c = 0; c < 2; ++c) coff[c] = (((c * 4 + quad) ^ (li & 7)) << 4);
    auto compute = [&](int bb) {
        #pragma unroll
        for (int c = 0; c < 2; ++c) {
            half8 f0e = *(const half8*)(k0e[bb] + c * 4096);
            half8 f1e = *(const half8*)(k1e[bb] + c * 4096);
            half8 f0o = *(const half8*)(k0e[bb] + c * 4096 + 512);
            half8 f1o = *(const half8*)(k1e[bb] + c * 4096 + 512);
            half8 pf[4];
            #pragma unroll
            for (int qt = 0; qt < 4; ++qt) {
                float4v se = {}, so = {};
                se = __builtin_amdgcn_mfma_f32_16x16x32_f16(f0e, qf[qt][0], se, 0, 0, 0);
                se = __builtin_amdgcn_mfma_f32_16x16x32_f16(f1e, qf[qt][1], se, 0, 0, 0);
                so = __builtin_amdgcn_mfma_f32_16x16x32_f16(f0o, qf[qt][0], so, 0, 0, 0);
                so = __builtin_amdgcn_mfma_f32_16x16x32_f16(f1o, qf[qt][1], so, 0, 0, 0);
                float pe[4], po[4];
                #pragma unroll
                for (int r = 0; r < 4; ++r) {
                    pe[r] = __builtin_amdgcn_exp2f(se[r]);
                    po[r] = __builtin_amdgcn_exp2f(so[r]);
                    lsum[qt] += pe[r] + po[r];
                }
                half4v a = __builtin_shufflevector(pk2(pe[0], pe[1]), pk2(pe[2], pe[3]), 0, 1, 2, 3);
                half4v o = __builtin_shufflevector(pk2(po[0], po[1]), pk2(po[2], po[3]), 0, 1, 2, 3);
                pf[qt] = __builtin_shufflevector(a, o, 0, 1, 2, 3, 4, 5, 6, 7);
            }
            #pragma unroll
            for (int dt = 0; dt < 4; ++dt) {
                half8 vf = *(const half8*)(vBq[bb] + dt * 2048 + coff[c]);
                #pragma unroll
                for (int qt = 0; qt < 4; ++qt)
                    O[qt][dt] = __builtin_amdgcn_mfma_f32_16x16x32_f16(pf[qt], vf, O[qt][dt], 0, 0, 0);
            }
        }
    };
    stage(0);
    for (int it = 0; it < 8; ++it) {
        __syncthreads();
        stage(1);
        compute(0);
        __syncthreads();
        if (it < 7) stage(0);
        compute(1);
    }
    // ---- split-K merge through (now free) tile LDS: high-kpos waves deposit, low add ----
    __syncthreads();
    float* Obuf = (float*)KtA;            // 32 KB: pair hh at +hh*4096 floats
    float* Lbuf = (float*)VtA;            // lsum: pair hh at +hh*256 floats
    if (strm == 1) {
        #pragma unroll
        for (int qt = 0; qt < 4; ++qt) {
            #pragma unroll
            for (int dt = 0; dt < 4; ++dt)
                ((float4v*)(Obuf + hh * 4096))[(qt * 4 + dt) * 64 + lane] = O[qt][dt];
            Lbuf[hh * 256 + qt * 64 + lane] = lsum[qt];
        }
    }
    __syncthreads();
    if (strm == 1) return;
    #pragma unroll
    for (int qt = 0; qt < 4; ++qt) {
        #pragma unroll
        for (int dt = 0; dt < 4; ++dt) {
            float4v o2 = ((float4v*)(Obuf + hh * 4096))[(qt * 4 + dt) * 64 + lane];
            O[qt][dt] += o2;
        }
        lsum[qt] += Lbuf[hh * 256 + qt * 64 + lane];
    }
    // epilogue: cross-quad l reduction, then out = O/l
    #pragma unroll
    for (int qt = 0; qt < 4; ++qt) {
        float l = lsum[qt];
        l += __shfl_xor(l, 16);
        l += __shfl_xor(l, 32);
        #pragma unroll
        for (int r = 0; r < 4; ++r) {
            float lr = __shfl(l, quad * 4 + r);
            float inv = 1.0f / lr;
            int q = q0 + qt * 16 + quad * 4 + r;
            float* orow = out + ((size_t)(b * 2048 + q)) * 512 + h * 64;
            #pragma unroll
            for (int dt = 0; dt < 4; ++dt) orow[dt * 16 + li] = O[qt][dt][r] * inv;
        }
    }
}

extern "C" void kernel_launch(void* const* d_in, const int* in_sizes, int n_in,
                              void* d_out, int out_size, void* d_ws, size_t ws_size,
                              hipStream_t stream) {
    const float* x  = (const float*)d_in[0];
    const float* wq = (const float*)d_in[1];
    const float* wk = (const float*)d_in[2];
    const float* wv = (const float*)d_in[3];
    float* out = (float*)d_out;
    char* ws = (char*)d_ws;
    // ws layout (bytes): xh 8M | Wt 1.5M | Q 8M | K 8M | Vt 8M  = 35,127,296 total
    _Float16* xh = (_Float16*)(ws);
    _Float16* wt = (_Float16*)(ws + 8388608);
    _Float16* Qm = (_Float16*)(ws + 9961472);
    _Float16* Km = (_Float16*)(ws + 18350080);
    _Float16* Vt = (_Float16*)(ws + 26738688);
    if (ws_size < 35127296u) return;
    mha_prep<<<4288, 256, 0, stream>>>(x, wq, wk, wv, xh, wt);
    mha_qkv<<<dim3(64, 12), 256, 0, stream>>>(xh, wt, Qm, Km, Vt);
    mha_attn<<<512, 256, 0, stream>>>(Qm, Km, Vt, out);
}

// Round 13
// 132.606 us; speedup vs baseline: 1.2294x; 1.0240x over previous
//
#include <hip/hip_runtime.h>

// MHA: B=4, S=2048, D=512, H=8, DH=64. fp32 in/out, f16 MFMA internally.
typedef _Float16 half8  __attribute__((ext_vector_type(8)));
typedef _Float16 half4v __attribute__((ext_vector_type(4)));
typedef _Float16 half2v __attribute__((ext_vector_type(2)));
typedef __fp16   fp16x2 __attribute__((ext_vector_type(2)));
typedef float    float4v __attribute__((ext_vector_type(4)));

#define CSC 0.18033688f  /* DH^-0.5 * log2(e) */

__device__ __forceinline__ void async16(const _Float16* g, void* l) {
    __builtin_amdgcn_global_load_lds((const __attribute__((address_space(1))) void*)g,
                                     (__attribute__((address_space(3))) void*)l, 16, 0, 0);
}

__device__ __forceinline__ half2v pk2(float a, float b) {
    return __builtin_bit_cast(half2v, __builtin_amdgcn_cvt_pkrtz(a, b));
}

// ---------------- fused prep: blocks [0,4096) cast x -> f16; [4096,4288) transpose W ----------------
__global__ __launch_bounds__(256) void mha_prep(const float* __restrict__ x,
    const float* __restrict__ wq, const float* __restrict__ wk, const float* __restrict__ wv,
    _Float16* __restrict__ xh, _Float16* __restrict__ wt) {
    __shared__ __align__(16) _Float16 T[64][72];  // [dh][dl], padded (W branch only)
    const int tid = threadIdx.x;
    if (blockIdx.x < 4096) {
        int t = blockIdx.x * 256 + tid;  // 1048576 float4s
        float4v v = ((const float4v*)x)[t];
        half4v o;
        #pragma unroll
        for (int i = 0; i < 4; ++i) o[i] = (_Float16)v[i];
        ((half4v*)xh)[t] = o;
        return;
    }
    const int blk = blockIdx.x - 4096;        // 192 = mat(3) x h(8) x dtile(8)
    const int dt = blk & 7, h = (blk >> 3) & 7, mat = blk >> 6;
    const float* w = ((mat == 0) ? wq : (mat == 1) ? wk : wv) + h * 32768 + dt * 64 * 64;
    #pragma unroll
    for (int i = 0; i < 4; ++i) {
        int s = tid + i * 256;                // 0..1023: dl = s>>4, c4 = s&15
        int dl = s >> 4, c4 = s & 15;
        float4v v = ((const float4v*)(w + (size_t)dl * 64))[c4];
        #pragma unroll
        for (int e = 0; e < 4; ++e) T[c4 * 4 + e][dl] = (_Float16)v[e];
    }
    __syncthreads();
    #pragma unroll
    for (int i = 0; i < 2; ++i) {
        int s = tid + i * 256;                // 0..511: dh = s>>3, c8 = s&7
        int dh = s >> 3, c8 = s & 7;
        half8 o;
        #pragma unroll
        for (int e = 0; e < 8; ++e) o[e] = T[dh][c8 * 8 + e];
        *(half8*)(wt + (size_t)((mat * 8 + h) * 64 + dh) * 512 + dt * 64 + c8 * 8) = o;
    }
}

// ---------------- QKV projection: C[8192][1536] = xh[8192][512] * Wt^T ----------------
// Epilogue for Q/K now transposes through LDS -> 16B coalesced stores (was 64x 2B scatter).
__global__ __launch_bounds__(256, 3) void mha_qkv(const _Float16* __restrict__ xh,
    const _Float16* __restrict__ wt, _Float16* __restrict__ Qm, _Float16* __restrict__ Km,
    _Float16* __restrict__ Vt) {
    __shared__ __align__(16) char smem[34816];  // staging: A[0:16K) B[16K:32K); epilogue: 128x272B
    _Float16* Ash[2] = { (_Float16*)smem,           (_Float16*)(smem + 8192)  };
    _Float16* Bsh[2] = { (_Float16*)(smem + 16384), (_Float16*)(smem + 24576) };
    const int tid = threadIdx.x;
    const int lane = tid & 63, wave = tid >> 6;
    const int quad = lane >> 4, li = lane & 15;
    const int m0 = blockIdx.x * 128, n0 = blockIdx.y * 128;
    float4v acc[4][4] = {};
    const int r0 = tid >> 2, c0 = (tid & 3) ^ ((r0 >> 1) & 3);
    const int s1 = 256 + tid, r1 = s1 >> 2, c1 = (s1 & 3) ^ ((r1 >> 1) & 3);
    const _Float16* gA0 = xh + (size_t)(m0 + r0) * 512 + c0 * 8;
    const _Float16* gA1 = xh + (size_t)(m0 + r1) * 512 + c1 * 8;
    const _Float16* gB0 = wt + (size_t)(n0 + r0) * 512 + c0 * 8;
    const _Float16* gB1 = wt + (size_t)(n0 + r1) * 512 + c1 * 8;
    const int wr = (wave >> 1) * 64, wc = (wave & 1) * 64;
    const char* aB[2]; const char* bB[2];
    #pragma unroll
    for (int bb = 0; bb < 2; ++bb) {
        aB[bb] = (const char*)Ash[bb] + (wr + li) * 64 + ((quad ^ ((li >> 1) & 3)) << 4);
        bB[bb] = (const char*)Bsh[bb] + (wc + li) * 64 + ((quad ^ ((li >> 1) & 3)) << 4);
    }
    auto stage = [&](int bb, int kk) {
        async16(gA0 + kk, (char*)Ash[bb] + wave * 1024);
        async16(gA1 + kk, (char*)Ash[bb] + 4096 + wave * 1024);
        async16(gB0 + kk, (char*)Bsh[bb] + wave * 1024);
        async16(gB1 + kk, (char*)Bsh[bb] + 4096 + wave * 1024);
    };
    auto compute = [&](int bb) {
        half8 af[4], bf[4];
        #pragma unroll
        for (int mt = 0; mt < 4; ++mt) af[mt] = *(const half8*)(aB[bb] + mt * 1024);
        #pragma unroll
        for (int nt = 0; nt < 4; ++nt) bf[nt] = *(const half8*)(bB[bb] + nt * 1024);
        #pragma unroll
        for (int mt = 0; mt < 4; ++mt)
            #pragma unroll
            for (int nt = 0; nt < 4; ++nt)
                acc[mt][nt] = __builtin_amdgcn_mfma_f32_16x16x32_f16(af[mt], bf[nt], acc[mt][nt], 0, 0, 0);
    };
    stage(0, 0);
    for (int kk = 0; kk < 512; kk += 64) {
        __syncthreads();
        stage(1, kk + 32);
        compute(0);
        __syncthreads();
        if (kk + 64 < 512) stage(0, kk + 64);
        compute(1);
    }
    const int mat = n0 >> 9;  // 0=Q 1=K 2=V (uniform per block)
    if (mat == 2) {  // V^T[bh][dh][s]: 8B stores along s (unchanged)
        #pragma unroll
        for (int mt = 0; mt < 4; ++mt) {
            int m = m0 + wr + mt * 16 + quad * 4;
            int b = m >> 11, s = m & 2047;
            #pragma unroll
            for (int nt = 0; nt < 4; ++nt) {
                int n = n0 + wc + nt * 16 + li;
                int h = (n >> 6) & 7, dh = n & 63;
                int bh = b * 8 + h;
                half4v pkv;
                #pragma unroll
                for (int r = 0; r < 4; ++r) pkv[r] = (_Float16)acc[mt][nt][r];
                *(half4v*)(Vt + ((size_t)bh * 64 + dh) * 2048 + s) = pkv;
            }
        }
    } else {  // Q/K: transpose tile through LDS, then 16B coalesced stores
        _Float16* dst = (mat == 0) ? Qm : Km;
        const float osc = (mat == 0) ? CSC : 1.0f;  // fold scale*log2e into Q
        __syncthreads();  // staging LDS no longer needed by any wave
        char* Tb = smem;  // 128 rows x 272 B (128 f16 + 16B pad)
        #pragma unroll
        for (int mt = 0; mt < 4; ++mt) {
            int rbase = wr + mt * 16 + quad * 4;
            #pragma unroll
            for (int nt = 0; nt < 4; ++nt) {
                int col = wc + nt * 16 + li;
                #pragma unroll
                for (int r = 0; r < 4; ++r)
                    *(_Float16*)(Tb + (rbase + r) * 272 + col * 2) = (_Float16)(acc[mt][nt][r] * osc);
            }
        }
        __syncthreads();
        const int h0 = (n0 >> 6) & 7;  // base head of this 128-col tile (h0, h0+1)
        #pragma unroll
        for (int i = 0; i < 8; ++i) {
            int c = i * 256 + tid;     // 0..2047 chunks of 16B
            int row = c >> 4, j8 = c & 15;
            half8 v = *(const half8*)(Tb + row * 272 + j8 * 16);
            int m = m0 + row;
            int b = m >> 11, s = m & 2047;
            int bh = b * 8 + h0 + (j8 >> 3);
            *(half8*)(dst + ((size_t)bh * 2048 + s) * 64 + (j8 & 7) * 8) = v;
        }
    }
}

// ---------------- flash attention: split-K + q_wave=64 (R12, unchanged) ----------------
__global__ __launch_bounds__(256, 2) void mha_attn(const _Float16* __restrict__ Qm,
    const _Float16* __restrict__ Km, const _Float16* __restrict__ Vt, float* __restrict__ out) {
    __shared__ __align__(16) _Float16 KtA[4][64 * 64];   // [stream*2+buf][kpos][d], 8KB each
    __shared__ __align__(16) _Float16 VtA[4][64 * 64];   // [stream*2+buf][d][kpos], 8KB each
    const int tid = threadIdx.x, lane = tid & 63, wave = tid >> 6;
    const int quad = lane >> 4, li = lane & 15;
    const int strm = wave & 1, hh = wave >> 1;
    const int flat = blockIdx.x;
    const int qb = (flat >> 3) & 15;
    const int bh = ((flat >> 7) << 3) | (flat & 7);
    const int b = bh >> 3, h = bh & 7;
    const _Float16* Qg = Qm + (size_t)bh * 2048 * 64;
    const _Float16* Kg = Km + (size_t)bh * 2048 * 64 + (size_t)strm * 1024 * 64;
    const _Float16* Vg = Vt + (size_t)bh * 64 * 2048 + (size_t)strm * 1024;
    const int q0 = qb * 128 + hh * 64;  // wave handles 64 q (4 tiles of 16)
    half8 qf[4][2];
    #pragma unroll
    for (int qt = 0; qt < 4; ++qt)
        #pragma unroll
        for (int ds = 0; ds < 2; ++ds)
            qf[qt][ds] = *(const half8*)(Qg + (size_t)(q0 + qt * 16 + li) * 64 + ds * 32 + quad * 8);
    float4v O[4][4] = {};
    float lsum[4] = {0.f, 0.f, 0.f, 0.f};
    char* Kst[2]; char* Vst[2];
    #pragma unroll
    for (int bb = 0; bb < 2; ++bb) {
        Kst[bb] = (char*)KtA + (strm * 2 + bb) * 8192;
        Vst[bb] = (char*)VtA + (strm * 2 + bb) * 8192;
    }
    const _Float16* pK[4]; const _Float16* pV[4];
    #pragma unroll
    for (int is = 0; is < 4; ++is) {
        int c = is * 128 + hh * 64 + lane;    // chunk 0..511
        int rk = c >> 3, sck = c & 7;
        int swk = (rk & 3) | (((rk >> 3) & 1) << 2);
        int rv = c >> 3, cv = (c & 7) ^ (rv & 7);
        pK[is] = Kg + (size_t)rk * 64 + (sck ^ swk) * 8;
        pV[is] = Vg + (size_t)rv * 2048 + cv * 8;
    }
    auto stage = [&](int bb) {
        #pragma unroll
        for (int is = 0; is < 4; ++is) {
            async16(pK[is], Kst[bb] + is * 2048 + hh * 1024);
            async16(pV[is], Vst[bb] + is * 2048 + hh * 1024);
            pK[is] += 4096;  // next 64 kpos rows
            pV[is] += 64;    // next 64 kpos cols
        }
    };
    const int rowE = ((li >> 2) << 3) | (li & 3);
    const int swzE = (li & 3) | (((li >> 2) & 1) << 2);
    const char *k0e[2], *k1e[2], *vBq[2];
    #pragma unroll
    for (int bb = 0; bb < 2; ++bb) {
        k0e[bb] = Kst[bb] + rowE * 128 + ((quad ^ swzE) << 4);
        k1e[bb] = Kst[bb] + rowE * 128 + (((quad + 4) ^ swzE) << 4);
        vBq[bb] = Vst[bb] + li * 128;
    }
    int coff[2];
    #pragma unroll
    for (int c = 0; c < 2; ++c) coff[c] = (((c * 4 + quad) ^ (li & 7)) << 4);
    auto compute = [&](int bb) {
        #pragma unroll
        for (int c = 0; c < 2; ++c) {
            half8 f0e = *(const half8*)(k0e[bb] + c * 4096);
            half8 f1e = *(const half8*)(k1e[bb] + c * 4096);
            half8 f0o = *(const half8*)(k0e[bb] + c * 4096 + 512);
            half8 f1o = *(const half8*)(k1e[bb] + c * 4096 + 512);
            half8 pf[4];
            #pragma unroll
            for (int qt = 0; qt < 4; ++qt) {
                float4v se = {}, so = {};
                se = __builtin_amdgcn_mfma_f32_16x16x32_f16(f0e, qf[qt][0], se, 0, 0, 0);
                se = __builtin_amdgcn_mfma_f32_16x16x32_f16(f1e, qf[qt][1], se, 0, 0, 0);
                so = __builtin_amdgcn_mfma_f32_16x16x32_f16(f0o, qf[qt][0], so, 0, 0, 0);
                so = __builtin_amdgcn_mfma_f32_16x16x32_f16(f1o, qf[qt][1], so, 0, 0, 0);
                float pe[4], po[4];
                #pragma unroll
                for (int r = 0; r < 4; ++r) {
                    pe[r] = __builtin_amdgcn_exp2f(se[r]);
                    po[r] = __builtin_amdgcn_exp2f(so[r]);
                    lsum[qt] += pe[r] + po[r];
                }
                half4v a = __builtin_shufflevector(pk2(pe[0], pe[1]), pk2(pe[2], pe[3]), 0, 1, 2, 3);
                half4v o = __builtin_shufflevector(pk2(po[0], po[1]), pk2(po[2], po[3]), 0, 1, 2, 3);
                pf[qt] = __builtin_shufflevector(a, o, 0, 1, 2, 3, 4, 5, 6, 7);
            }
            #pragma unroll
            for (int dt = 0; dt < 4; ++dt) {
                half8 vf = *(const half8*)(vBq[bb] + dt * 2048 + coff[c]);
                #pragma unroll
                for (int qt = 0; qt < 4; ++qt)
                    O[qt][dt] = __builtin_amdgcn_mfma_f32_16x16x32_f16(pf[qt], vf, O[qt][dt], 0, 0, 0);
            }
        }
    };
    stage(0);
    for (int it = 0; it < 8; ++it) {
        __syncthreads();
        stage(1);
        compute(0);
        __syncthreads();
        if (it < 7) stage(0);
        compute(1);
    }
    // ---- split-K merge through (now free) tile LDS: high-kpos waves deposit, low add ----
    __syncthreads();
    float* Obuf = (float*)KtA;            // 32 KB: pair hh at +hh*4096 floats
    float* Lbuf = (float*)VtA;            // lsum: pair hh at +hh*256 floats
    if (strm == 1) {
        #pragma unroll
        for (int qt = 0; qt < 4; ++qt) {
            #pragma unroll
            for (int dt = 0; dt < 4; ++dt)
                ((float4v*)(Obuf + hh * 4096))[(qt * 4 + dt) * 64 + lane] = O[qt][dt];
            Lbuf[hh * 256 + qt * 64 + lane] = lsum[qt];
        }
    }
    __syncthreads();
    if (strm == 1) return;
    #pragma unroll
    for (int qt = 0; qt < 4; ++qt) {
        #pragma unroll
        for (int dt = 0; dt < 4; ++dt) {
            float4v o2 = ((float4v*)(Obuf + hh * 4096))[(qt * 4 + dt) * 64 + lane];
            O[qt][dt] += o2;
        }
        lsum[qt] += Lbuf[hh * 256 + qt * 64 + lane];
    }
    // epilogue: cross-quad l reduction, then out = O/l
    #pragma unroll
    for (int qt = 0; qt < 4; ++qt) {
        float l = lsum[qt];
        l += __shfl_xor(l, 16);
        l += __shfl_xor(l, 32);
        #pragma unroll
        for (int r = 0; r < 4; ++r) {
            float lr = __shfl(l, quad * 4 + r);
            float inv = 1.0f / lr;
            int q = q0 + qt * 16 + quad * 4 + r;
            float* orow = out + ((size_t)(b * 2048 + q)) * 512 + h * 64;
            #pragma unroll
            for (int dt = 0; dt < 4; ++dt) orow[dt * 16 + li] = O[qt][dt][r] * inv;
        }
    }
}

extern "C" void kernel_launch(void* const* d_in, const int* in_sizes, int n_in,
                              void* d_out, int out_size, void* d_ws, size_t ws_size,
                              hipStream_t stream) {
    const float* x  = (const float*)d_in[0];
    const float* wq = (const float*)d_in[1];
    const float* wk = (const float*)d_in[2];
    const float* wv = (const float*)d_in[3];
    float* out = (float*)d_out;
    char* ws = (char*)d_ws;
    // ws layout (bytes): xh 8M | Wt 1.5M | Q 8M | K 8M | Vt 8M  = 35,127,296 total
    _Float16* xh = (_Float16*)(ws);
    _Float16* wt = (_Float16*)(ws + 8388608);
    _Float16* Qm = (_Float16*)(ws + 9961472);
    _Float16* Km = (_Float16*)(ws + 18350080);
    _Float16* Vt = (_Float16*)(ws + 26738688);
    if (ws_size < 35127296u) return;
    mha_prep<<<4288, 256, 0, stream>>>(x, wq, wk, wv, xh, wt);
    mha_qkv<<<dim3(64, 12), 256, 0, stream>>>(xh, wt, Qm, Km, Vt);
    mha_attn<<<512, 256, 0, stream>>>(Qm, Km, Vt, out);
}